// Round 1
// baseline (93.479 us; speedup 1.0000x reference)
//
#include <hip/hip_runtime.h>

// Problem constants (KANLayer): B=1024, I=128, O=128, H=5
#define Bsz 1024
#define Isz 128
#define Osz 128
#define Hsz 5
#define Esz (Osz * Isz)   // 16384 edges
#define GB 32    // batches per block (16.5 KB LDS -> up to 9 blocks/CU)
#define NG (Bsz / GB)
#define UF 4     // batches in flight; 46 params + 4 chains ~= 78 live VGPRs < 84
#define NPAR 45  // transposed param slices: 5 w1 + 5 b1 + 25 w2 + 5 b2 + 5 w3

// ---------------------------------------------------------------------------
// Param-layout transpose: pt[s*Esz + e] = param_s(edge e).
// Thread-per-(s,e) element; writes fully coalesced; reads stride-5/25 floats
// (<=5x line overfetch over 3 MB, L2-absorbed, one-time). Branch on s is
// wave-uniform: Esz % 256 == 0 so each block lies in a single s-slice.
// ---------------------------------------------------------------------------
__global__ __launch_bounds__(256)
void transpose_params(const float* __restrict__ W1, const float* __restrict__ B1,
                      const float* __restrict__ W2, const float* __restrict__ B2,
                      const float* __restrict__ W3, float* __restrict__ pt) {
    const int idx = blockIdx.x * 256 + threadIdx.x;   // < NPAR * Esz
    const int s = idx >> 14;            // / Esz
    const int e = idx & (Esz - 1);      // % Esz
    float v;
    if (s < 5)       v = W1[e * Hsz + s];
    else if (s < 10) v = B1[e * Hsz + (s - 5)];
    else if (s < 35) v = W2[e * (Hsz * Hsz) + (s - 10)];
    else if (s < 40) v = B2[e * Hsz + (s - 35)];
    else             v = W3[e * Hsz + (s - 40)];
    pt[idx] = v;
}

// ---------------------------------------------------------------------------
// DPP wave64 sum: quad_perm xor1, xor2, row_half_mirror, row_mirror,
// row_bcast:15, row_bcast:31. Full sum lands in lane 63. All VALU
// (GCNDPPCombine folds the dpp mov into v_add_f32_dpp), zero DS-pipe.
// ---------------------------------------------------------------------------
template <int CTRL>
__device__ __forceinline__ float dpp_add(float s) {
    int t = __builtin_amdgcn_update_dpp(0, __builtin_bit_cast(int, s),
                                        CTRL, 0xf, 0xf, true);
    return s + __builtin_bit_cast(float, t);
}
__device__ __forceinline__ float wave_sum64_lane63(float s) {
    s = dpp_add<0xB1>(s);    // quad_perm [1,0,3,2]  (xor 1)
    s = dpp_add<0x4E>(s);    // quad_perm [2,3,0,1]  (xor 2)
    s = dpp_add<0x141>(s);   // row_half_mirror      (xor 4)
    s = dpp_add<0x140>(s);   // row_mirror           (xor 8)
    s = dpp_add<0x142>(s);   // row_bcast:15
    s = dpp_add<0x143>(s);   // row_bcast:31
    return s;                // lane 63 holds the full 64-lane sum
}

// ---------------------------------------------------------------------------
// Edge-stationary kernel. Thread <-> one edge (o,i); 46 params in VGPRs.
// R9 change: params come from the TRANSPOSED layout pt[s][e] -> all 46
// gather loads are lane-consecutive (4 lines/load instead of ~64), removing
// ~29 us of memory-pipe serialization in the prologue. Compute loop,
// LDS layout, occupancy (256,6) untouched.
// ---------------------------------------------------------------------------
__global__ __launch_bounds__(256, 6)
void kan_kernel(const float* __restrict__ x,
                const float* __restrict__ pt,   // [NPAR][Esz] transposed params
                const float* __restrict__ B3,
                float* __restrict__ out) {
    __shared__ float xs[GB * Isz];        // 16 KB: x[b0:b0+32][0:128]
    __shared__ float partial[4 * GB];     // 512 B: per-wave reduced rows

    const int tid = threadIdx.x;
    const int ob  = blockIdx.x & 63;      // o-pair index (fastest)
    const int g   = blockIdx.x >> 6;      // batch group 0..31
    const int b0  = g * GB;
    const int w   = tid >> 6;             // wave 0..3
    const int l   = tid & 63;             // lane
    const int o   = 2 * ob + (w >> 1);    // waves 0,1 -> o0; waves 2,3 -> o1
    const int i   = 64 * (w & 1) + l;     // i-half per wave
    const int e   = o * Isz + i;

    // --- stage x tile (coalesced float4, once) ---
    {
        const float4* xg = (const float4*)(x + (size_t)b0 * Isz);
        float4* xs4 = (float4*)xs;
        #pragma unroll
        for (int j = 0; j < (GB * Isz / 4) / 256; ++j)   // 4 iters
            xs4[tid + 256 * j] = xg[tid + 256 * j];
    }

    // --- my edge's 46 params -> VGPRs, gathered once (coalesced: lane-adjacent e) ---
    const float* __restrict__ p = pt + e;
    float w1[Hsz], b1[Hsz], w2[Hsz * Hsz], b2[Hsz], w3[Hsz];
    #pragma unroll
    for (int h = 0; h < Hsz; ++h) {
        w1[h] = p[(0  + h) * Esz];
        b1[h] = p[(5  + h) * Esz];
        b2[h] = p[(35 + h) * Esz];
        w3[h] = p[(40 + h) * Esz];
    }
    #pragma unroll
    for (int j = 0; j < Hsz * Hsz; ++j) w2[j] = p[(10 + j) * Esz];

    // batch-invariant b3 term: sum over this wave's 64 i's, once
    const float s3w = wave_sum64_lane63(B3[e]);
    const float s3  = __builtin_bit_cast(float,
        __builtin_amdgcn_readlane(__builtin_bit_cast(int, s3w), 63));

    __syncthreads();

    float res = 0.0f;   // out-partial for batch b0+l (l < GB), this i-half

    #pragma unroll
    for (int bl = 0; bl < GB; bl += UF) {
        float y[UF];
        #pragma unroll
        for (int u = 0; u < UF; ++u) {
            const float a = xs[(bl + u) * Isz + i];

            // layer 1: scalar -> H, leaky_relu(0.01)
            float h1[Hsz];
            #pragma unroll
            for (int h = 0; h < Hsz; ++h) {
                float v = fmaf(a, w1[h], b1[h]);
                h1[h] = fmaxf(v, 0.01f * v);
            }
            // layer 2 (H->H, lrelu) + layer 3 (H->1, b3 hoisted out)
            float yy = 0.0f;
            #pragma unroll
            for (int k = 0; k < Hsz; ++k) {
                float s = b2[k];
                #pragma unroll
                for (int h = 0; h < Hsz; ++h)
                    s = fmaf(h1[h], w2[k * Hsz + h], s);
                s = fmaxf(s, 0.01f * s);
                yy = fmaf(s, w3[k], yy);
            }
            y[u] = yy;
        }

        // DPP reduce each chain; park lane-63 total in lane bl+u.
        #pragma unroll
        for (int u = 0; u < UF; ++u) {
            const float s = wave_sum64_lane63(y[u]);
            const float tot = __builtin_bit_cast(float,
                __builtin_amdgcn_readlane(__builtin_bit_cast(int, s), 63));
            if (l == bl + u) res = tot;
        }
    }

    if (l < GB) partial[w * GB + l] = res + s3;
    __syncthreads();

    // combine i-half waves and store: 64 outputs per block, each written once
    if (tid < 2 * GB) {
        const int bl = tid & (GB - 1);
        const int oo = tid >> 5;
        const float v = partial[(2 * oo) * GB + bl] + partial[(2 * oo + 1) * GB + bl];
        out[(size_t)(b0 + bl) * Osz + (2 * ob + oo)] = v;
    }
}

extern "C" void kernel_launch(void* const* d_in, const int* in_sizes, int n_in,
                              void* d_out, int out_size, void* d_ws, size_t ws_size,
                              hipStream_t stream) {
    const float* x  = (const float*)d_in[0];
    const float* W1 = (const float*)d_in[1];
    const float* B1 = (const float*)d_in[2];
    const float* W2 = (const float*)d_in[3];
    const float* B2 = (const float*)d_in[4];
    const float* W3 = (const float*)d_in[5];
    const float* B3 = (const float*)d_in[6];
    float* out = (float*)d_out;
    float* pt  = (float*)d_ws;   // 45 * 16384 * 4 B = 2.95 MB << ws_size

    // 1) one-time param-layout transpose into workspace
    transpose_params<<<dim3(NPAR * Esz / 256), dim3(256), 0, stream>>>(
        W1, B1, W2, B2, W3, pt);

    // 2) main kernel, unchanged structure
    const dim3 grid((Osz / 2) * NG);   // 64 o-pairs x 32 batch groups = 2048 blocks
    kan_kernel<<<grid, dim3(256), 0, stream>>>(x, pt, B3, out);
}